// Round 10
// baseline (152.711 us; speedup 1.0000x reference)
//
#include <hip/hip_runtime.h>
#include <math.h>

// Fused HENN MLP: gather -> segment_sum -> Linear(256,256)+ReLU -> Linear(256,1) -> sigmoid
//
// R10 pipeline (3 launches) — split wins over fusion (R9 post-mortem: fusing
// MFMA into the gather kernel collapses gather occupancy 60%->18%):
//  1. prep (fused):  x->bf16 (nt loads), W1->bf16, seg_ptr build
//  2. henn_gather:   R7 engine VERBATIM (66us, service-rate-pinned):
//                    scalarized pair stream (SGPR indices -> s_load tnodes),
//                    two 8-deep u2 banks double-buffered, f32 accumulate,
//                    wave-uniform flush, nt stores of Zg. 128thr, VGPR~32,
//                    launch_bounds(128,8) -> ~60% occupancy.
//  3. henn_mlp2:     NEW: 32 segs / 128 threads / 16KB LDS / no occupancy pin
//                    (3125 blocks, ~10 blocks/CU LDS-limited -> staging of
//                    block N overlaps MFMA of block N-1). Two-half MFMA
//                    structure (R9-verified): acc[2][4] live (32 VGPR),
//                    pacc[2][4] carried across halves. Epilogue: shfl reduce,
//                    sigmoid, store.
//
// Falls back to the R4-style fused f32 kernel if ws_size is too small.

typedef __attribute__((ext_vector_type(8))) short bf16x8;
typedef __attribute__((ext_vector_type(4))) float f32x4;
typedef __attribute__((ext_vector_type(4))) float f4;
typedef __attribute__((ext_vector_type(4))) unsigned u4;
typedef __attribute__((ext_vector_type(2))) unsigned u2;

__device__ __forceinline__ ushort f2bf(float f) {   // RNE f32->bf16
  unsigned u = __float_as_uint(f);
  return (ushort)((u + 0x7FFF + ((u >> 16) & 1)) >> 16);
}
__device__ __forceinline__ unsigned pack2(float lo, float hi) {
  return (unsigned)f2bf(lo) | ((unsigned)f2bf(hi) << 16);
}

#define PREP_CONVX_BLOCKS 2048
#define PREP_W1_BLOCKS    64

__global__ __launch_bounds__(256) void prep(
    const float* __restrict__ x, ushort* __restrict__ xb, long nx,
    const float* __restrict__ W1, ushort* __restrict__ W1b,
    const int* __restrict__ tids, int* __restrict__ ptr, int P, int E,
    int do_convx)
{
  const int b = blockIdx.x;
  if (b < PREP_CONVX_BLOCKS) {
    if (!do_convx) return;
    long i = ((long)b * 256 + threadIdx.x) * 8;
    const long stride = (long)PREP_CONVX_BLOCKS * 256 * 8;
    for (; i < nx; i += stride) {
      const f4 v0 = __builtin_nontemporal_load((const f4*)(x + i));
      const f4 v1 = __builtin_nontemporal_load((const f4*)(x + i + 4));
      u4 o;
      o.x = pack2(v0.x, v0.y); o.y = pack2(v0.z, v0.w);
      o.z = pack2(v1.x, v1.y); o.w = pack2(v1.z, v1.w);
      *(u4*)(xb + i) = o;                      // keep xb cacheable (hot buffer)
    }
  } else if (b < PREP_CONVX_BLOCKS + PREP_W1_BLOCKS) {
    const int base = ((b - PREP_CONVX_BLOCKS) * 256 + threadIdx.x) * 4;
    if (base < 256 * 256) {
      const f4 v = *(const f4*)(W1 + base);
      u2 o; o.x = pack2(v.x, v.y); o.y = pack2(v.z, v.w);
      *(u2*)(W1b + base) = o;
    }
  } else {
    const int p = (b - PREP_CONVX_BLOCKS - PREP_W1_BLOCKS) * 256 + threadIdx.x;
    if (p >= P) return;
    const int v = tids[p];
    const int prev = (p == 0) ? -1 : tids[p - 1];
    for (int e = prev + 1; e <= v; ++e) ptr[e] = p;
    if (p == P - 1) {
      for (int e = v + 1; e <= E; ++e) ptr[e] = P;
    }
  }
}

__global__ __launch_bounds__(128, 8) void henn_gather(
    const ushort* __restrict__ xb,
    const int* __restrict__ tnodes,
    const int* __restrict__ ptr,
    ushort* __restrict__ Zg,
    int E)
{
  const int lane = threadIdx.x & 63;
  const int wid  = threadIdx.x >> 6;             // 0..1
  const int e0   = blockIdx.x * 16 + wid * 8;    // this wave's 8 segments
  if (e0 >= E) return;
  const int nseg = min(8, E - e0);

  int bnd = 0;
  if (lane <= 8) bnd = ptr[min(e0 + lane, E)];   // bounds for segs e0..e0+8
  const int plo = __builtin_amdgcn_readfirstlane(__shfl(bnd, 0));
  const int phi = __builtin_amdgcn_readfirstlane(__shfl(bnd, nseg));
  const int total = phi - plo;                   // SGPR

  const char* xbB = (const char*)xb;
  const int lb = lane * 8;                       // byte offset within 512B row
  char* zB = (char*)Zg + (size_t)e0 * 512 + lb;

  float a0 = 0.f, a1 = 0.f, a2 = 0.f, a3 = 0.f;
  int s = 0;
  int hi_s = __builtin_amdgcn_readfirstlane(__shfl(bnd, 1));

#define FLUSHCHK(PCUR)                                                        \
  while ((PCUR) >= hi_s) {            /* wave-uniform segment flush */        \
    u2 oz; oz.x = pack2(a0, a1); oz.y = pack2(a2, a3);                        \
    __builtin_nontemporal_store(oz, (u2*)(zB + (size_t)s * 512));             \
    a0 = a1 = a2 = a3 = 0.f;                                                  \
    ++s; hi_s = __builtin_amdgcn_readfirstlane(__shfl(bnd, min(s + 1, 8)));   \
  }

#define ACCV(V)                                                               \
  a0 += __uint_as_float((V).x << 16);                                         \
  a1 += __uint_as_float((V).x & 0xffff0000u);                                 \
  a2 += __uint_as_float((V).y << 16);                                         \
  a3 += __uint_as_float((V).y & 0xffff0000u);

  if (total > 0) {
    const int tmax = total - 1;
    u2 va[8], vb[8];
    // prologue: fill both banks; indices wave-uniform -> tnodes via s_load
#pragma unroll
    for (int k = 0; k < 8; ++k) {
      const int p = plo + min(k, tmax);
      va[k] = *(const u2*)(xbB + (size_t)tnodes[p] * 512 + lb);
    }
#pragma unroll
    for (int k = 0; k < 8; ++k) {
      const int p = plo + min(8 + k, tmax);
      vb[k] = *(const u2*)(xbB + (size_t)tnodes[p] * 512 + lb);
    }

    for (int j = 0; j < total; j += 16) {
      // consume bank A (pairs j..j+8)
#pragma unroll
      for (int k = 0; k < 8; ++k) {
        const int pc = j + k;
        if (pc < total) { FLUSHCHK(plo + pc) ACCV(va[k]) }
      }
      // refill bank A for pairs [j+16, j+24)
#pragma unroll
      for (int k = 0; k < 8; ++k) {
        const int p = plo + min(j + 16 + k, tmax);
        va[k] = *(const u2*)(xbB + (size_t)tnodes[p] * 512 + lb);
      }
      // consume bank B (pairs j+8..j+16)
#pragma unroll
      for (int k = 0; k < 8; ++k) {
        const int pc = j + 8 + k;
        if (pc < total) { FLUSHCHK(plo + pc) ACCV(vb[k]) }
      }
      // refill bank B for pairs [j+24, j+32)
#pragma unroll
      for (int k = 0; k < 8; ++k) {
        const int p = plo + min(j + 24 + k, tmax);
        vb[k] = *(const u2*)(xbB + (size_t)tnodes[p] * 512 + lb);
      }
    }
  }
  // flush remaining segments (incl. trailing empties)
  while (s < nseg) {
    u2 oz; oz.x = pack2(a0, a1); oz.y = pack2(a2, a3);
    __builtin_nontemporal_store(oz, (u2*)(zB + (size_t)s * 512));
    a0 = a1 = a2 = a3 = 0.f;
    ++s;
  }
#undef FLUSHCHK
#undef ACCV
}

// NEW: 32 segs / 128 threads / 16KB LDS / no occupancy pin
__global__ __launch_bounds__(128) void henn_mlp2(
    const ushort* __restrict__ Zg,
    const ushort* __restrict__ W1b,
    const float* __restrict__ b1,
    const float* __restrict__ W2,
    const float* __restrict__ b2,
    float* __restrict__ out,
    int E)
{
  __shared__ __align__(16) ushort Zb[32 * 256];   // 16 KB, XOR-swizzled
  const int tid  = threadIdx.x;
  const int lane = tid & 63;
  const int wid  = tid >> 6;            // 0..1
  const int l15  = lane & 15;
  const int l4   = lane >> 4;
  const int eb   = blockIdx.x * 32;

  // ---- stage contiguous 16 KB -> swizzled LDS (byte ^= (row&7)<<4) ----
  const char* src = (const char*)(Zg + (size_t)eb * 256);
#pragma unroll
  for (int i = 0; i < 8; ++i) {
    const int off = i * 2048 + tid * 16;
    const u4 v = __builtin_nontemporal_load((const u4*)(src + off));
    const int row = off >> 9;
    *(u4*)((char*)Zb + (off ^ ((row & 7) << 4))) = v;
  }
  __syncthreads();

  // ---- Y = relu(Z@W1^T+b1); pacc += W2 .* Y, two nt-halves (R9-verified) ---
  const int n0 = wid * 128;
  float pacc[2][4];
#pragma unroll
  for (int mt = 0; mt < 2; ++mt)
#pragma unroll
    for (int r = 0; r < 4; ++r) pacc[mt][r] = 0.f;

#pragma unroll
  for (int half = 0; half < 2; ++half) {
    f32x4 acc[2][4];                 // only 32 VGPRs of accumulator live
#pragma unroll
    for (int mt = 0; mt < 2; ++mt)
#pragma unroll
      for (int nt = 0; nt < 4; ++nt)
        acc[mt][nt] = (f32x4){0.f, 0.f, 0.f, 0.f};

#pragma unroll
    for (int kk = 0; kk < 8; ++kk) {
      bf16x8 a[2];
#pragma unroll
      for (int mt = 0; mt < 2; ++mt) {
        const int row = mt * 16 + l15;
        const int raddr = row * 512 + kk * 64 + l4 * 16;
        a[mt] = *(const bf16x8*)((const char*)Zb + (raddr ^ ((row & 7) << 4)));
      }
#pragma unroll
      for (int nt = 0; nt < 4; ++nt) {
        const int h = n0 + (half * 4 + nt) * 16 + l15;
        const bf16x8 b = *(const bf16x8*)(W1b + (size_t)h * 256 + kk * 32 + l4 * 8);
#pragma unroll
        for (int mt = 0; mt < 2; ++mt)
          acc[mt][nt] = __builtin_amdgcn_mfma_f32_16x16x32_bf16(a[mt], b, acc[mt][nt], 0, 0, 0);
      }
    }
#pragma unroll
    for (int nt = 0; nt < 4; ++nt) {
      const int h = n0 + (half * 4 + nt) * 16 + l15;
      const float b1h = b1[h];
      const float w2h = W2[h];
#pragma unroll
      for (int mt = 0; mt < 2; ++mt)
#pragma unroll
        for (int r = 0; r < 4; ++r) {
          const float y = acc[mt][nt][r] + b1h;
          pacc[mt][r] = fmaf(w2h, fmaxf(y, 0.f), pacc[mt][r]);
        }
    }
  }
  __syncthreads();   // all Zb reads done; reuse as reduction scratch

  float* red = (float*)Zb;          // [2][32]
#pragma unroll
  for (int mt = 0; mt < 2; ++mt) {
#pragma unroll
    for (int r = 0; r < 4; ++r) {
      float p = pacc[mt][r];
      p += __shfl_xor(p, 1);
      p += __shfl_xor(p, 2);
      p += __shfl_xor(p, 4);
      p += __shfl_xor(p, 8);
      if (l15 == 0) red[wid * 32 + mt * 16 + l4 * 4 + r] = p;
    }
  }
  __syncthreads();

  if (tid < 32) {
    const int e = eb + tid;
    if (e < E) {
      const float v = red[tid] + red[32 + tid] + b2[0];
      out[e] = 1.f / (1.f + expf(-v));
    }
  }
}

// ---------------- R4 fused fallback (ws too small for split path) ----------
__global__ __launch_bounds__(256, 4) void henn_main(
    const float* __restrict__ x,
    const int* __restrict__ tnodes,
    const int* __restrict__ ptr,
    const ushort* __restrict__ W1b,
    const float* __restrict__ b1,
    const float* __restrict__ W2,
    const float* __restrict__ b2,
    float* __restrict__ out,
    int E)
{
  __shared__ __align__(16) ushort Zb[64 * 256];
  const int tid  = threadIdx.x;
  const int wid  = tid >> 6;
  const int lane = tid & 63;
  const int l15  = lane & 15;
  const int l4   = lane >> 4;
  const int e0   = blockIdx.x * 64;

  int bidx = e0 + wid * 16 + lane;
  int bnd = 0;
  if (lane < 17) bnd = ptr[min(bidx, E)];

  for (int s = 0; s < 16; ++s) {
    const int lo = __shfl(bnd, s);
    const int hi = __shfl(bnd, s + 1);
    float4 a0 = {0,0,0,0}, a1 = {0,0,0,0}, a2 = {0,0,0,0}, a3 = {0,0,0,0};
    for (int base = lo; base < hi; base += 64) {
      const int cnt = min(64, hi - base);
      const int nd = (lane < cnt) ? tnodes[base + lane] : 0;
      const int rounds = (cnt + 3) >> 2;
      for (int r = 0; r < rounds; ++r) {
        const int idx = r * 4 + l4;
        const int node = __shfl(nd, min(idx, cnt - 1));
        if (idx < cnt) {
          const float4* rowp = (const float4*)(x + (size_t)node * 256) + l15;
          const float4 v0 = rowp[0];
          const float4 v1 = rowp[16];
          const float4 v2 = rowp[32];
          const float4 v3 = rowp[48];
          a0.x += v0.x; a0.y += v0.y; a0.z += v0.z; a0.w += v0.w;
          a1.x += v1.x; a1.y += v1.y; a1.z += v1.z; a1.w += v1.w;
          a2.x += v2.x; a2.y += v2.y; a2.z += v2.z; a2.w += v2.w;
          a3.x += v3.x; a3.y += v3.y; a3.z += v3.z; a3.w += v3.w;
        }
      }
    }
    a0.x += __shfl_xor(a0.x,16); a0.y += __shfl_xor(a0.y,16); a0.z += __shfl_xor(a0.z,16); a0.w += __shfl_xor(a0.w,16);
    a0.x += __shfl_xor(a0.x,32); a0.y += __shfl_xor(a0.y,32); a0.z += __shfl_xor(a0.z,32); a0.w += __shfl_xor(a0.w,32);
    a1.x += __shfl_xor(a1.x,16); a1.y += __shfl_xor(a1.y,16); a1.z += __shfl_xor(a1.z,16); a1.w += __shfl_xor(a1.w,16);
    a1.x += __shfl_xor(a1.x,32); a1.y += __shfl_xor(a1.y,32); a1.z += __shfl_xor(a1.z,32); a1.w += __shfl_xor(a1.w,32);
    a2.x += __shfl_xor(a2.x,16); a2.y += __shfl_xor(a2.y,16); a2.z += __shfl_xor(a2.z,16); a2.w += __shfl_xor(a2.w,16);
    a2.x += __shfl_xor(a2.x,32); a2.y += __shfl_xor(a2.y,32); a2.z += __shfl_xor(a2.z,32); a2.w += __shfl_xor(a2.w,32);
    a3.x += __shfl_xor(a3.x,16); a3.y += __shfl_xor(a3.y,16); a3.z += __shfl_xor(a3.z,16); a3.w += __shfl_xor(a3.w,16);
    a3.x += __shfl_xor(a3.x,32); a3.y += __shfl_xor(a3.y,32); a3.z += __shfl_xor(a3.z,32); a3.w += __shfl_xor(a3.w,32);
    float4 m = (l4 == 0) ? a0 : (l4 == 1) ? a1 : (l4 == 2) ? a2 : a3;
    const int row = wid * 16 + s;
    ushort4 o; o.x = f2bf(m.x); o.y = f2bf(m.y); o.z = f2bf(m.z); o.w = f2bf(m.w);
    const int waddr = row * 512 + lane * 8;
    *(ushort4*)((char*)Zb + (waddr ^ ((row & 7) << 4))) = o;
  }
  __syncthreads();

  const int n0 = wid * 64;
  f32x4 acc[4][4];
#pragma unroll
  for (int mt = 0; mt < 4; ++mt)
#pragma unroll
    for (int nt = 0; nt < 4; ++nt)
      acc[mt][nt] = (f32x4){0.f, 0.f, 0.f, 0.f};
#pragma unroll
  for (int kk = 0; kk < 8; ++kk) {
    bf16x8 a[4];
#pragma unroll
    for (int mt = 0; mt < 4; ++mt) {
      const int row = mt * 16 + l15;
      const int raddr = row * 512 + kk * 64 + l4 * 16;
      a[mt] = *(const bf16x8*)((const char*)Zb + (raddr ^ ((row & 7) << 4)));
    }
#pragma unroll
    for (int nt = 0; nt < 4; ++nt) {
      const int h = n0 + nt * 16 + l15;
      const bf16x8 b = *(const bf16x8*)(W1b + (size_t)h * 256 + kk * 32 + l4 * 8);
#pragma unroll
      for (int mt = 0; mt < 4; ++mt)
        acc[mt][nt] = __builtin_amdgcn_mfma_f32_16x16x32_bf16(a[mt], b, acc[mt][nt], 0, 0, 0);
    }
  }
  __syncthreads();

  float b1h[4], w2v[4];
#pragma unroll
  for (int nt = 0; nt < 4; ++nt) {
    const int h = n0 + nt * 16 + l15;
    b1h[nt] = b1[h];
    w2v[nt] = W2[h];
  }
  float* red = (float*)Zb;
#pragma unroll
  for (int mt = 0; mt < 4; ++mt) {
#pragma unroll
    for (int r = 0; r < 4; ++r) {
      float p = 0.f;
#pragma unroll
      for (int nt = 0; nt < 4; ++nt) {
        const float y = acc[mt][nt][r] + b1h[nt];
        p = fmaf(w2v[nt], fmaxf(y, 0.f), p);
      }
      p += __shfl_xor(p, 1);
      p += __shfl_xor(p, 2);
      p += __shfl_xor(p, 4);
      p += __shfl_xor(p, 8);
      if (l15 == 0) red[wid * 64 + mt * 16 + l4 * 4 + r] = p;
    }
  }
  __syncthreads();

  if (tid < 64) {
    const int e = e0 + tid;
    if (e < E) {
      const float v = red[tid] + red[64 + tid] + red[128 + tid] + red[192 + tid] + b2[0];
      out[e] = 1.f / (1.f + expf(-v));
    }
  }
}

extern "C" void kernel_launch(void* const* d_in, const int* in_sizes, int n_in,
                              void* d_out, int out_size, void* d_ws, size_t ws_size,
                              hipStream_t stream) {
  const float* x      = (const float*)d_in[0];
  const int*   tnodes = (const int*)d_in[1];
  const int*   tids   = (const int*)d_in[2];
  const float* W1     = (const float*)d_in[3];
  const float* b1     = (const float*)d_in[4];
  const float* W2     = (const float*)d_in[5];
  const float* b2     = (const float*)d_in[6];
  (void)n_in;

  const int P       = in_sizes[1];        // 800000
  const int E       = out_size;           // 100000
  const int n_nodes = in_sizes[0] / 256;  // 100000

  const size_t OFF_W1B  = 512 * 1024;
  const size_t OFF_XB   = 1024 * 1024;
  const size_t xb_bytes = (size_t)n_nodes * 512;
  const size_t off_zg   = OFF_XB + ((xb_bytes + 65535) & ~(size_t)65535);
  const size_t zg_bytes = (size_t)E * 512 + 65536;
  const size_t need     = off_zg + zg_bytes;

  int*    seg_ptr = (int*)d_ws;
  ushort* W1b     = (ushort*)((char*)d_ws + OFF_W1B);
  ushort* xb      = (ushort*)((char*)d_ws + OFF_XB);
  ushort* Zg      = (ushort*)((char*)d_ws + off_zg);

  const int split_ok   = (ws_size >= need) ? 1 : 0;
  const int prep_grid  = PREP_CONVX_BLOCKS + PREP_W1_BLOCKS + (P + 255) / 256;
  prep<<<prep_grid, 256, 0, stream>>>(x, xb, (long)n_nodes * 256, W1, W1b,
                                      tids, seg_ptr, P, E, split_ok);

  if (split_ok) {
    const int gblocks = (E + 15) / 16;
    henn_gather<<<gblocks, 128, 0, stream>>>(xb, tnodes, seg_ptr, Zg, E);
    const int mblocks = (E + 31) / 32;
    henn_mlp2<<<mblocks, 128, 0, stream>>>(Zg, W1b, b1, W2, b2, (float*)d_out, E);
  } else {
    const int blocks = (E + 63) / 64;
    henn_main<<<blocks, 256, 0, stream>>>(x, tnodes, seg_ptr, W1b, b1, W2, b2,
                                          (float*)d_out, E);
  }
}

// Round 11
// 134.538 us; speedup vs baseline: 1.1351x; 1.1351x over previous
//
#include <hip/hip_runtime.h>
#include <math.h>

// Fused HENN MLP: gather -> segment_sum -> Linear(256,256)+ReLU -> Linear(256,1) -> sigmoid
//
// R11 pipeline (3 launches):
//  1. prep (fused):  x->bf16 (nt loads), W1->bf16, seg_ptr build   [R7 verbatim]
//  2. henn_gather:   R7 engine VERBATIM (65.5us, service-rate-pinned at
//                    ~6.2 TB/s logical delivery across 4 structural variants)
//  3. henn_mlp:      128 segs/block, 256 thr, 64KB LDS, launch_bounds(256,2).
//                    R10 post-mortem: mlp is W1-AMORTIZATION-bound — each
//                    block reads the full 128KB W1b, so M must be large.
//                    128 rows halve W1 traffic (100MB) and each B-frag feeds
//                    8 MFMAs. nt processed in two halves (R9-verified):
//                    acc[8][2]=64 VGPR live + pacc[8][4] carried; ~190 VGPR
//                    peak < 256 cap from (256,2) -> no spill (R8 lesson).
//
// Falls back to the R4-style fused f32 kernel if ws_size is too small.

typedef __attribute__((ext_vector_type(8))) short bf16x8;
typedef __attribute__((ext_vector_type(4))) float f32x4;
typedef __attribute__((ext_vector_type(4))) float f4;
typedef __attribute__((ext_vector_type(4))) unsigned u4;
typedef __attribute__((ext_vector_type(2))) unsigned u2;

__device__ __forceinline__ ushort f2bf(float f) {   // RNE f32->bf16
  unsigned u = __float_as_uint(f);
  return (ushort)((u + 0x7FFF + ((u >> 16) & 1)) >> 16);
}
__device__ __forceinline__ unsigned pack2(float lo, float hi) {
  return (unsigned)f2bf(lo) | ((unsigned)f2bf(hi) << 16);
}

#define PREP_CONVX_BLOCKS 2048
#define PREP_W1_BLOCKS    64

__global__ __launch_bounds__(256) void prep(
    const float* __restrict__ x, ushort* __restrict__ xb, long nx,
    const float* __restrict__ W1, ushort* __restrict__ W1b,
    const int* __restrict__ tids, int* __restrict__ ptr, int P, int E,
    int do_convx)
{
  const int b = blockIdx.x;
  if (b < PREP_CONVX_BLOCKS) {
    if (!do_convx) return;
    long i = ((long)b * 256 + threadIdx.x) * 8;
    const long stride = (long)PREP_CONVX_BLOCKS * 256 * 8;
    for (; i < nx; i += stride) {
      const f4 v0 = __builtin_nontemporal_load((const f4*)(x + i));
      const f4 v1 = __builtin_nontemporal_load((const f4*)(x + i + 4));
      u4 o;
      o.x = pack2(v0.x, v0.y); o.y = pack2(v0.z, v0.w);
      o.z = pack2(v1.x, v1.y); o.w = pack2(v1.z, v1.w);
      *(u4*)(xb + i) = o;                      // keep xb cacheable (hot buffer)
    }
  } else if (b < PREP_CONVX_BLOCKS + PREP_W1_BLOCKS) {
    const int base = ((b - PREP_CONVX_BLOCKS) * 256 + threadIdx.x) * 4;
    if (base < 256 * 256) {
      const f4 v = *(const f4*)(W1 + base);
      u2 o; o.x = pack2(v.x, v.y); o.y = pack2(v.z, v.w);
      *(u2*)(W1b + base) = o;
    }
  } else {
    const int p = (b - PREP_CONVX_BLOCKS - PREP_W1_BLOCKS) * 256 + threadIdx.x;
    if (p >= P) return;
    const int v = tids[p];
    const int prev = (p == 0) ? -1 : tids[p - 1];
    for (int e = prev + 1; e <= v; ++e) ptr[e] = p;
    if (p == P - 1) {
      for (int e = v + 1; e <= E; ++e) ptr[e] = P;
    }
  }
}

__global__ __launch_bounds__(128, 8) void henn_gather(
    const ushort* __restrict__ xb,
    const int* __restrict__ tnodes,
    const int* __restrict__ ptr,
    ushort* __restrict__ Zg,
    int E)
{
  const int lane = threadIdx.x & 63;
  const int wid  = threadIdx.x >> 6;             // 0..1
  const int e0   = blockIdx.x * 16 + wid * 8;    // this wave's 8 segments
  if (e0 >= E) return;
  const int nseg = min(8, E - e0);

  int bnd = 0;
  if (lane <= 8) bnd = ptr[min(e0 + lane, E)];   // bounds for segs e0..e0+8
  const int plo = __builtin_amdgcn_readfirstlane(__shfl(bnd, 0));
  const int phi = __builtin_amdgcn_readfirstlane(__shfl(bnd, nseg));
  const int total = phi - plo;                   // SGPR

  const char* xbB = (const char*)xb;
  const int lb = lane * 8;                       // byte offset within 512B row
  char* zB = (char*)Zg + (size_t)e0 * 512 + lb;

  float a0 = 0.f, a1 = 0.f, a2 = 0.f, a3 = 0.f;
  int s = 0;
  int hi_s = __builtin_amdgcn_readfirstlane(__shfl(bnd, 1));

#define FLUSHCHK(PCUR)                                                        \
  while ((PCUR) >= hi_s) {            /* wave-uniform segment flush */        \
    u2 oz; oz.x = pack2(a0, a1); oz.y = pack2(a2, a3);                        \
    __builtin_nontemporal_store(oz, (u2*)(zB + (size_t)s * 512));             \
    a0 = a1 = a2 = a3 = 0.f;                                                  \
    ++s; hi_s = __builtin_amdgcn_readfirstlane(__shfl(bnd, min(s + 1, 8)));   \
  }

#define ACCV(V)                                                               \
  a0 += __uint_as_float((V).x << 16);                                         \
  a1 += __uint_as_float((V).x & 0xffff0000u);                                 \
  a2 += __uint_as_float((V).y << 16);                                         \
  a3 += __uint_as_float((V).y & 0xffff0000u);

  if (total > 0) {
    const int tmax = total - 1;
    u2 va[8], vb[8];
    // prologue: fill both banks; indices wave-uniform -> tnodes via s_load
#pragma unroll
    for (int k = 0; k < 8; ++k) {
      const int p = plo + min(k, tmax);
      va[k] = *(const u2*)(xbB + (size_t)tnodes[p] * 512 + lb);
    }
#pragma unroll
    for (int k = 0; k < 8; ++k) {
      const int p = plo + min(8 + k, tmax);
      vb[k] = *(const u2*)(xbB + (size_t)tnodes[p] * 512 + lb);
    }

    for (int j = 0; j < total; j += 16) {
      // consume bank A (pairs j..j+8)
#pragma unroll
      for (int k = 0; k < 8; ++k) {
        const int pc = j + k;
        if (pc < total) { FLUSHCHK(plo + pc) ACCV(va[k]) }
      }
      // refill bank A for pairs [j+16, j+24)
#pragma unroll
      for (int k = 0; k < 8; ++k) {
        const int p = plo + min(j + 16 + k, tmax);
        va[k] = *(const u2*)(xbB + (size_t)tnodes[p] * 512 + lb);
      }
      // consume bank B (pairs j+8..j+16)
#pragma unroll
      for (int k = 0; k < 8; ++k) {
        const int pc = j + 8 + k;
        if (pc < total) { FLUSHCHK(plo + pc) ACCV(vb[k]) }
      }
      // refill bank B for pairs [j+24, j+32)
#pragma unroll
      for (int k = 0; k < 8; ++k) {
        const int p = plo + min(j + 24 + k, tmax);
        vb[k] = *(const u2*)(xbB + (size_t)tnodes[p] * 512 + lb);
      }
    }
  }
  // flush remaining segments (incl. trailing empties)
  while (s < nseg) {
    u2 oz; oz.x = pack2(a0, a1); oz.y = pack2(a2, a3);
    __builtin_nontemporal_store(oz, (u2*)(zB + (size_t)s * 512));
    a0 = a1 = a2 = a3 = 0.f;
    ++s;
  }
#undef FLUSHCHK
#undef ACCV
}

// R11: 128 segs / 256 threads / 64KB LDS / (256,2) — W1 amortized over M=128
__global__ __launch_bounds__(256, 2) void henn_mlp(
    const ushort* __restrict__ Zg,
    const ushort* __restrict__ W1b,
    const float* __restrict__ b1,
    const float* __restrict__ W2,
    const float* __restrict__ b2,
    float* __restrict__ out,
    int E)
{
  __shared__ __align__(16) ushort Zb[128 * 256];   // 64 KB, XOR-swizzled
  const int tid  = threadIdx.x;
  const int wid  = tid >> 6;            // 0..3
  const int lane = tid & 63;
  const int l15  = lane & 15;
  const int l4   = lane >> 4;
  const int eb   = blockIdx.x * 128;

  // ---- stage contiguous 64 KB -> swizzled LDS (byte ^= (row&7)<<4) ----
  const char* src = (const char*)(Zg + (size_t)eb * 256);
#pragma unroll
  for (int i = 0; i < 16; ++i) {
    const int off = i * 4096 + tid * 16;
    const u4 v = __builtin_nontemporal_load((const u4*)(src + off));
    const int row = off >> 9;
    *(u4*)((char*)Zb + (off ^ ((row & 7) << 4))) = v;
  }
  __syncthreads();

  // ---- Y = relu(Z@W1^T+b1); pacc += W2 .* Y; wave owns h in [64*wid,+64) ---
  // mt = 8 row-tiles (128 rows); nt = 4 col-tiles processed in two halves of 2
  // so live acc = [8][2] f32x4 = 64 VGPR; pacc [8][4] floats carried.
  const int n0 = wid * 64;
  float pacc[8][4];
#pragma unroll
  for (int mt = 0; mt < 8; ++mt)
#pragma unroll
    for (int r = 0; r < 4; ++r) pacc[mt][r] = 0.f;

#pragma unroll
  for (int half = 0; half < 2; ++half) {
    f32x4 acc[8][2];
#pragma unroll
    for (int mt = 0; mt < 8; ++mt)
#pragma unroll
      for (int nt = 0; nt < 2; ++nt)
        acc[mt][nt] = (f32x4){0.f, 0.f, 0.f, 0.f};

#pragma unroll
    for (int kk = 0; kk < 8; ++kk) {
      bf16x8 a[8];
#pragma unroll
      for (int mt = 0; mt < 8; ++mt) {
        const int row = mt * 16 + l15;
        const int raddr = row * 512 + kk * 64 + l4 * 16;
        a[mt] = *(const bf16x8*)((const char*)Zb + (raddr ^ ((row & 7) << 4)));
      }
#pragma unroll
      for (int nt = 0; nt < 2; ++nt) {
        const int h = n0 + (half * 2 + nt) * 16 + l15;
        const bf16x8 b = *(const bf16x8*)(W1b + (size_t)h * 256 + kk * 32 + l4 * 8);
#pragma unroll
        for (int mt = 0; mt < 8; ++mt)
          acc[mt][nt] = __builtin_amdgcn_mfma_f32_16x16x32_bf16(a[mt], b, acc[mt][nt], 0, 0, 0);
      }
    }
    // fold this half into the layer-2 partial
#pragma unroll
    for (int nt = 0; nt < 2; ++nt) {
      const int h = n0 + (half * 2 + nt) * 16 + l15;
      const float b1h = b1[h];
      const float w2h = W2[h];
#pragma unroll
      for (int mt = 0; mt < 8; ++mt)
#pragma unroll
        for (int r = 0; r < 4; ++r) {
          const float y = acc[mt][nt][r] + b1h;
          pacc[mt][r] = fmaf(w2h, fmaxf(y, 0.f), pacc[mt][r]);
        }
    }
  }
  __syncthreads();   // all Zb reads done; reuse as reduction scratch

  // ---- epilogue: reduce over l15 within wave, then across 4 waves ----------
  float* red = (float*)Zb;          // [4][128]
#pragma unroll
  for (int mt = 0; mt < 8; ++mt) {
#pragma unroll
    for (int r = 0; r < 4; ++r) {
      float p = pacc[mt][r];
      p += __shfl_xor(p, 1);
      p += __shfl_xor(p, 2);
      p += __shfl_xor(p, 4);
      p += __shfl_xor(p, 8);
      if (l15 == 0) red[wid * 128 + mt * 16 + l4 * 4 + r] = p;
    }
  }
  __syncthreads();

  if (tid < 128) {
    const int e = eb + tid;
    if (e < E) {
      const float v = red[tid] + red[128 + tid] + red[256 + tid] + red[384 + tid] + b2[0];
      out[e] = 1.f / (1.f + expf(-v));
    }
  }
}

// ---------------- R4 fused fallback (ws too small for split path) ----------
__global__ __launch_bounds__(256, 4) void henn_main(
    const float* __restrict__ x,
    const int* __restrict__ tnodes,
    const int* __restrict__ ptr,
    const ushort* __restrict__ W1b,
    const float* __restrict__ b1,
    const float* __restrict__ W2,
    const float* __restrict__ b2,
    float* __restrict__ out,
    int E)
{
  __shared__ __align__(16) ushort Zb[64 * 256];
  const int tid  = threadIdx.x;
  const int wid  = tid >> 6;
  const int lane = tid & 63;
  const int l15  = lane & 15;
  const int l4   = lane >> 4;
  const int e0   = blockIdx.x * 64;

  int bidx = e0 + wid * 16 + lane;
  int bnd = 0;
  if (lane < 17) bnd = ptr[min(bidx, E)];

  for (int s = 0; s < 16; ++s) {
    const int lo = __shfl(bnd, s);
    const int hi = __shfl(bnd, s + 1);
    float4 a0 = {0,0,0,0}, a1 = {0,0,0,0}, a2 = {0,0,0,0}, a3 = {0,0,0,0};
    for (int base = lo; base < hi; base += 64) {
      const int cnt = min(64, hi - base);
      const int nd = (lane < cnt) ? tnodes[base + lane] : 0;
      const int rounds = (cnt + 3) >> 2;
      for (int r = 0; r < rounds; ++r) {
        const int idx = r * 4 + l4;
        const int node = __shfl(nd, min(idx, cnt - 1));
        if (idx < cnt) {
          const float4* rowp = (const float4*)(x + (size_t)node * 256) + l15;
          const float4 v0 = rowp[0];
          const float4 v1 = rowp[16];
          const float4 v2 = rowp[32];
          const float4 v3 = rowp[48];
          a0.x += v0.x; a0.y += v0.y; a0.z += v0.z; a0.w += v0.w;
          a1.x += v1.x; a1.y += v1.y; a1.z += v1.z; a1.w += v1.w;
          a2.x += v2.x; a2.y += v2.y; a2.z += v2.z; a2.w += v2.w;
          a3.x += v3.x; a3.y += v3.y; a3.z += v3.z; a3.w += v3.w;
        }
      }
    }
    a0.x += __shfl_xor(a0.x,16); a0.y += __shfl_xor(a0.y,16); a0.z += __shfl_xor(a0.z,16); a0.w += __shfl_xor(a0.w,16);
    a0.x += __shfl_xor(a0.x,32); a0.y += __shfl_xor(a0.y,32); a0.z += __shfl_xor(a0.z,32); a0.w += __shfl_xor(a0.w,32);
    a1.x += __shfl_xor(a1.x,16); a1.y += __shfl_xor(a1.y,16); a1.z += __shfl_xor(a1.z,16); a1.w += __shfl_xor(a1.w,16);
    a1.x += __shfl_xor(a1.x,32); a1.y += __shfl_xor(a1.y,32); a1.z += __shfl_xor(a1.z,32); a1.w += __shfl_xor(a1.w,32);
    a2.x += __shfl_xor(a2.x,16); a2.y += __shfl_xor(a2.y,16); a2.z += __shfl_xor(a2.z,16); a2.w += __shfl_xor(a2.w,16);
    a2.x += __shfl_xor(a2.x,32); a2.y += __shfl_xor(a2.y,32); a2.z += __shfl_xor(a2.z,32); a2.w += __shfl_xor(a2.w,32);
    a3.x += __shfl_xor(a3.x,16); a3.y += __shfl_xor(a3.y,16); a3.z += __shfl_xor(a3.z,16); a3.w += __shfl_xor(a3.w,16);
    a3.x += __shfl_xor(a3.x,32); a3.y += __shfl_xor(a3.y,32); a3.z += __shfl_xor(a3.z,32); a3.w += __shfl_xor(a3.w,32);
    float4 m = (l4 == 0) ? a0 : (l4 == 1) ? a1 : (l4 == 2) ? a2 : a3;
    const int row = wid * 16 + s;
    ushort4 o; o.x = f2bf(m.x); o.y = f2bf(m.y); o.z = f2bf(m.z); o.w = f2bf(m.w);
    const int waddr = row * 512 + lane * 8;
    *(ushort4*)((char*)Zb + (waddr ^ ((row & 7) << 4))) = o;
  }
  __syncthreads();

  const int n0 = wid * 64;
  f32x4 acc[4][4];
#pragma unroll
  for (int mt = 0; mt < 4; ++mt)
#pragma unroll
    for (int nt = 0; nt < 4; ++nt)
      acc[mt][nt] = (f32x4){0.f, 0.f, 0.f, 0.f};
#pragma unroll
  for (int kk = 0; kk < 8; ++kk) {
    bf16x8 a[4];
#pragma unroll
    for (int mt = 0; mt < 4; ++mt) {
      const int row = mt * 16 + l15;
      const int raddr = row * 512 + kk * 64 + l4 * 16;
      a[mt] = *(const bf16x8*)((const char*)Zb + (raddr ^ ((row & 7) << 4)));
    }
#pragma unroll
    for (int nt = 0; nt < 4; ++nt) {
      const int h = n0 + nt * 16 + l15;
      const bf16x8 b = *(const bf16x8*)(W1b + (size_t)h * 256 + kk * 32 + l4 * 8);
#pragma unroll
      for (int mt = 0; mt < 4; ++mt)
        acc[mt][nt] = __builtin_amdgcn_mfma_f32_16x16x32_bf16(a[mt], b, acc[mt][nt], 0, 0, 0);
    }
  }
  __syncthreads();

  float b1h[4], w2v[4];
#pragma unroll
  for (int nt = 0; nt < 4; ++nt) {
    const int h = n0 + nt * 16 + l15;
    b1h[nt] = b1[h];
    w2v[nt] = W2[h];
  }
  float* red = (float*)Zb;
#pragma unroll
  for (int mt = 0; mt < 4; ++mt) {
#pragma unroll
    for (int r = 0; r < 4; ++r) {
      float p = 0.f;
#pragma unroll
      for (int nt = 0; nt < 4; ++nt) {
        const float y = acc[mt][nt][r] + b1h[nt];
        p = fmaf(w2v[nt], fmaxf(y, 0.f), p);
      }
      p += __shfl_xor(p, 1);
      p += __shfl_xor(p, 2);
      p += __shfl_xor(p, 4);
      p += __shfl_xor(p, 8);
      if (l15 == 0) red[wid * 64 + mt * 16 + l4 * 4 + r] = p;
    }
  }
  __syncthreads();

  if (tid < 64) {
    const int e = e0 + tid;
    if (e < E) {
      const float v = red[tid] + red[64 + tid] + red[128 + tid] + red[192 + tid] + b2[0];
      out[e] = 1.f / (1.f + expf(-v));
    }
  }
}

extern "C" void kernel_launch(void* const* d_in, const int* in_sizes, int n_in,
                              void* d_out, int out_size, void* d_ws, size_t ws_size,
                              hipStream_t stream) {
  const float* x      = (const float*)d_in[0];
  const int*   tnodes = (const int*)d_in[1];
  const int*   tids   = (const int*)d_in[2];
  const float* W1     = (const float*)d_in[3];
  const float* b1     = (const float*)d_in[4];
  const float* W2     = (const float*)d_in[5];
  const float* b2     = (const float*)d_in[6];
  (void)n_in;

  const int P       = in_sizes[1];        // 800000
  const int E       = out_size;           // 100000
  const int n_nodes = in_sizes[0] / 256;  // 100000

  const size_t OFF_W1B  = 512 * 1024;
  const size_t OFF_XB   = 1024 * 1024;
  const size_t xb_bytes = (size_t)n_nodes * 512;
  const size_t off_zg   = OFF_XB + ((xb_bytes + 65535) & ~(size_t)65535);
  const size_t zg_bytes = (size_t)E * 512 + 65536;   // pad covers OOB tile rows
  const size_t need     = off_zg + zg_bytes;

  int*    seg_ptr = (int*)d_ws;
  ushort* W1b     = (ushort*)((char*)d_ws + OFF_W1B);
  ushort* xb      = (ushort*)((char*)d_ws + OFF_XB);
  ushort* Zg      = (ushort*)((char*)d_ws + off_zg);

  const int split_ok   = (ws_size >= need) ? 1 : 0;
  const int prep_grid  = PREP_CONVX_BLOCKS + PREP_W1_BLOCKS + (P + 255) / 256;
  prep<<<prep_grid, 256, 0, stream>>>(x, xb, (long)n_nodes * 256, W1, W1b,
                                      tids, seg_ptr, P, E, split_ok);

  if (split_ok) {
    const int gblocks = (E + 15) / 16;
    henn_gather<<<gblocks, 128, 0, stream>>>(xb, tnodes, seg_ptr, Zg, E);
    const int mblocks = (E + 127) / 128;
    henn_mlp<<<mblocks, 256, 0, stream>>>(Zg, W1b, b1, W2, b2, (float*)d_out, E);
  } else {
    const int blocks = (E + 63) / 64;
    henn_main<<<blocks, 256, 0, stream>>>(x, tnodes, seg_ptr, W1b, b1, W2, b2,
                                          (float*)d_out, E);
  }
}